// Round 10
// baseline (443.223 us; speedup 1.0000x reference)
//
#include <hip/hip_runtime.h>

// Viterbi CRF decode: potentials [B,T,C] f32, transitions [C,C] f32 -> one-hot [B,T,C] f32
// B=256, T=1024, C=128.
//
// r10: ONE fused kernel, 256 threads (4 waves)/block, 1 block/batch/CU.
//  Phase 1 (fwd, inline asm): max-only DP. Per 16-lane row: 8 c's; per lane:
//   p-chunk i (8 p). Trans lives in fixed v64-v127 loaded inside the asm
//   (v[64+c*8+k] = T[8i+k][c8+c]) - allocator cannot spill it (r4-r8 lesson).
//   Per step: 2 ds_read_b128, 8 interleaved trees (4 pk_add + 3 max3 + 1 max),
//   32 DPP (xor1,xor2,ror4,ror8 select-free reduce - r7/r9-validated),
//   7 cndmask select, exec-masked {alpha->LDS, q->global}, lgkm(0)+barrier.
//   vs r9 (8 waves): half the DS traffic, half the barrier width.
//   q_t = PRE-pot max rows stashed in d_out; row 0 = zeros.
//  Phase 2 (bwd, C): transpose trans into LDS; wave 0 chases: M = q_t[tag]
//   (readlane), backpointer = first p with (q+pot)+T == M (bit-exact replay),
//   ballot+ffs; one-hot overwrites d_out. Fusion kills the 2nd launch and
//   reads q while L1/L2-warm.

typedef float f32x2 __attribute__((ext_vector_type(2)));
typedef unsigned int u32x4 __attribute__((ext_vector_type(4)));

constexpr int NB = 256;
constexpr int NT = 1024;
constexpr int NC = 128;

template <int CTRL>
__device__ __forceinline__ float fmax_dpp(float v) {
  int x = __builtin_amdgcn_update_dpp(__float_as_int(v), __float_as_int(v),
                                      CTRL, 0xF, 0xF, false);
  return fmaxf(v, __int_as_float(x));
}
__device__ __forceinline__ float wave_max_to_lane63(float m) {
  m = fmax_dpp<0x111>(m);  // row_shr:1
  m = fmax_dpp<0x112>(m);  // row_shr:2
  m = fmax_dpp<0x114>(m);  // row_shr:4
  m = fmax_dpp<0x118>(m);  // row_shr:8
  m = fmax_dpp<0x142>(m);  // row_bcast:15
  m = fmax_dpp<0x143>(m);  // row_bcast:31 -> lane63 has full max
  return m;
}

constexpr int ABUF = 192;  // alpha: p at float 12*(p>>3)+(p&7), double-buffered

// ---- asm building blocks ----

// trans load: v[64+c*8+k] = T[8i+k][c8+c]  (offset = 512k + 4c)
#define LDT(R, O) "global_load_dword v" R ", %[toff], %[strans] offset:" O "\n\t"

// two interleaved 8-max trees (temps v32-39 / v40-47), alpha in v56-63
#define TREE2(A0, A2, A4, A6, MDA, B0, B2, B4, B6, MDB)     \
  "v_pk_add_f32 v[32:33], v[56:57], v[" A0 "]\n\t"          \
  "v_pk_add_f32 v[40:41], v[56:57], v[" B0 "]\n\t"          \
  "v_pk_add_f32 v[34:35], v[58:59], v[" A2 "]\n\t"          \
  "v_pk_add_f32 v[42:43], v[58:59], v[" B2 "]\n\t"          \
  "v_pk_add_f32 v[36:37], v[60:61], v[" A4 "]\n\t"          \
  "v_pk_add_f32 v[44:45], v[60:61], v[" B4 "]\n\t"          \
  "v_pk_add_f32 v[38:39], v[62:63], v[" A6 "]\n\t"          \
  "v_pk_add_f32 v[46:47], v[62:63], v[" B6 "]\n\t"          \
  "v_max3_f32 v32, v32, v33, v34\n\t"                       \
  "v_max3_f32 v40, v40, v41, v42\n\t"                       \
  "v_max3_f32 v35, v35, v36, v37\n\t"                       \
  "v_max3_f32 v43, v43, v44, v45\n\t"                       \
  "v_max3_f32 v32, v32, v35, v38\n\t"                       \
  "v_max3_f32 v40, v40, v43, v46\n\t"                       \
  "v_max_f32 " MDA ", v32, v39\n\t"                         \
  "v_max_f32 " MDB ", v40, v47\n\t"

#define DPP8(CTL)                                                          \
  "v_max_f32_dpp v48, v48, v48 " CTL " row_mask:0xf bank_mask:0xf\n\t"     \
  "v_max_f32_dpp v49, v49, v49 " CTL " row_mask:0xf bank_mask:0xf\n\t"     \
  "v_max_f32_dpp v50, v50, v50 " CTL " row_mask:0xf bank_mask:0xf\n\t"     \
  "v_max_f32_dpp v51, v51, v51 " CTL " row_mask:0xf bank_mask:0xf\n\t"     \
  "v_max_f32_dpp v52, v52, v52 " CTL " row_mask:0xf bank_mask:0xf\n\t"     \
  "v_max_f32_dpp v53, v53, v53 " CTL " row_mask:0xf bank_mask:0xf\n\t"     \
  "v_max_f32_dpp v54, v54, v54 " CTL " row_mask:0xf bank_mask:0xf\n\t"     \
  "v_max_f32_dpp v55, v55, v55 " CTL " row_mask:0xf bank_mask:0xf\n\t"

#define STEP_S(RD, WR, PC, SOFF)                                           \
  "ds_read_b128 v[56:59], %[" RD "]\n\t"                                   \
  "ds_read_b128 v[60:63], %[" RD "] offset:16\n\t"                         \
  "s_waitcnt lgkmcnt(0)\n\t"                                               \
  TREE2("64:65","66:67","68:69","70:71","v48",                             \
        "72:73","74:75","76:77","78:79","v49")                             \
  TREE2("80:81","82:83","84:85","86:87","v50",                             \
        "88:89","90:91","92:93","94:95","v51")                             \
  TREE2("96:97","98:99","100:101","102:103","v52",                         \
        "104:105","106:107","108:109","110:111","v53")                     \
  TREE2("112:113","114:115","116:117","118:119","v54",                     \
        "120:121","122:123","124:125","126:127","v55")                     \
  DPP8("quad_perm:[1,0,3,2]")                                              \
  DPP8("quad_perm:[2,3,0,1]")                                              \
  DPP8("row_ror:4")                                                        \
  DPP8("row_ror:8")                                                        \
  "v_cndmask_b32 v32, v48, v49, %[selb0]\n\t"                              \
  "v_cndmask_b32 v33, v50, v51, %[selb0]\n\t"                              \
  "v_cndmask_b32 v34, v52, v53, %[selb0]\n\t"                              \
  "v_cndmask_b32 v35, v54, v55, %[selb0]\n\t"                              \
  "v_cndmask_b32 v32, v32, v33, %[selb1]\n\t"                              \
  "v_cndmask_b32 v34, v34, v35, %[selb1]\n\t"                              \
  "v_cndmask_b32 v32, v32, v34, %[selb2]\n\t"                              \
  "s_mov_b64 exec, %[wmask]\n\t"                                           \
  "v_add_f32 v33, v32, %[" PC "]\n\t"                                      \
  "ds_write_b32 %[" WR "], v33\n\t"                                        \
  "global_store_dword %[qoff], v32, %[sout] offset:" SOFF "\n\t"           \
  "s_mov_b64 exec, -1\n\t"                                                 \
  "s_waitcnt lgkmcnt(0)\n\t"                                               \
  "s_barrier\n\t"

__global__ __launch_bounds__(256, 1)
void crf_fused(const float* __restrict__ pot, const float* __restrict__ trans,
               float* __restrict__ out) {
  extern __shared__ __align__(16) float smem[];
  float* alpha = smem;            // 2*ABUF floats (1.5 KB)
  float* tTf = smem + 2 * ABUF;   // 16384 floats (64 KB), phase 2

  const int tid = threadIdx.x;
  const int b = blockIdx.x;
  const int w = tid >> 6;          // wave 0..3
  const int l = tid & 63;          // lane
  const int r = l >> 4;            // 16-lane row 0..3
  const int i = l & 15;            // p-chunk (p = 8i..8i+7)
  const int G = w * 4 + r;         // c-group 0..15, c8 = 8G
  const bool wr = (i >= 8);        // writer lanes: i=8..15 -> c' = i-8
  const int cw = 8 * G + (i & 7);  // writer's c (valid for all lanes)
  const int widx = 12 * G + (i & 7);

  const float* potb = pot + (size_t)b * NT * NC;
  float* outb = out + (size_t)b * NT * NC;

  // ---------------- phase 1: forward DP ----------------
  unsigned rda = (unsigned)(size_t)(alpha + 12 * i);
  unsigned rdb = (unsigned)(size_t)(alpha + ABUF + 12 * i);
  unsigned wra = (unsigned)(size_t)(alpha + widx);
  unsigned wrb = (unsigned)(size_t)(alpha + ABUF + widx);

  unsigned toff = (unsigned)((8 * i * NC + 8 * G) * 4);            // T[8i][c8]
  unsigned qoff = (unsigned)((1 * NC + cw) * 4);                   // q row 1
  unsigned poff = ((unsigned)b * (NT * NC) + 5 * NC + cw) * 4u;    // pot row 5
  unsigned long long strans = (unsigned long long)(size_t)trans;
  unsigned long long sout = (unsigned long long)(size_t)outb;
  unsigned long long pbase = (unsigned long long)(size_t)pot;
  u32x4 srd;
  srd.x = (unsigned)pbase;
  srd.y = (unsigned)(pbase >> 32) & 0xFFFFu;
  srd.z = (unsigned)(NB * NT * NC) * 4u;     // bounds: OOB load -> 0
  srd.w = 0x00020000u;
  unsigned long long selb0 = 0xAAAAAAAAAAAAAAAAull;  // lanes with l&1
  unsigned long long selb1 = 0xCCCCCCCCCCCCCCCCull;  // lanes with l&2
  unsigned long long selb2 = 0xF0F0F0F0F0F0F0F0ull;  // lanes with l&4
  unsigned long long wmask = 0xFF00FF00FF00FF00ull;  // lanes with l&8 (i>=8)
  int cnt = 254;

  float pc0 = potb[1 * NC + cw], pc1 = potb[2 * NC + cw];
  float pc2 = potb[3 * NC + cw], pc3 = potb[4 * NC + cw];
  float pn0 = 0.f, pn1 = 0.f, pn2 = 0.f, pn3 = 0.f;

  if (wr) {
    alpha[widx] = potb[cw];   // alpha_0 = pot[:,0,:]
    outb[cw] = 0.0f;          // q_0 := 0 (alpha_0 = 0 + pot_0)
  }
  __syncthreads();

  asm volatile(
      // trans -> v64..v127 (row-major: v[64+c*8+k] = T[8i+k][c8+c])
      LDT("64","0")   LDT("72","4")   LDT("80","8")   LDT("88","12")
      LDT("96","16")  LDT("104","20") LDT("112","24") LDT("120","28")
      LDT("65","512") LDT("73","516") LDT("81","520") LDT("89","524")
      LDT("97","528") LDT("105","532") LDT("113","536") LDT("121","540")
      LDT("66","1024") LDT("74","1028") LDT("82","1032") LDT("90","1036")
      LDT("98","1040") LDT("106","1044") LDT("114","1048") LDT("122","1052")
      LDT("67","1536") LDT("75","1540") LDT("83","1544") LDT("91","1548")
      LDT("99","1552") LDT("107","1556") LDT("115","1560") LDT("123","1564")
      LDT("68","2048") LDT("76","2052") LDT("84","2056") LDT("92","2060")
      LDT("100","2064") LDT("108","2068") LDT("116","2072") LDT("124","2076")
      LDT("69","2560") LDT("77","2564") LDT("85","2568") LDT("93","2572")
      LDT("101","2576") LDT("109","2580") LDT("117","2584") LDT("125","2588")
      LDT("70","3072") LDT("78","3076") LDT("86","3080") LDT("94","3084")
      LDT("102","3088") LDT("110","3092") LDT("118","3096") LDT("126","3100")
      LDT("71","3584") LDT("79","3588") LDT("87","3592") LDT("95","3596")
      LDT("103","3600") LDT("111","3604") LDT("119","3608") LDT("127","3612")
      "s_waitcnt vmcnt(0)\n\t"
      // pot prefetch rows 5..8
      "buffer_load_dword %[pn0], %[poff], %[srd], 0 offen\n\t"
      "buffer_load_dword %[pn1], %[poff], %[srd], 0 offen offset:512\n\t"
      "buffer_load_dword %[pn2], %[poff], %[srd], 0 offen offset:1024\n\t"
      "buffer_load_dword %[pn3], %[poff], %[srd], 0 offen offset:1536\n\t"
      "L_crfmain_%=:\n\t"
      STEP_S("rda", "wrb", "pc0", "0")
      STEP_S("rdb", "wra", "pc1", "512")
      STEP_S("rda", "wrb", "pc2", "1024")
      STEP_S("rdb", "wra", "pc3", "1536")
      "s_waitcnt vmcnt(4)\n\t"
      "v_mov_b32 %[pc0], %[pn0]\n\t"
      "v_mov_b32 %[pc1], %[pn1]\n\t"
      "v_mov_b32 %[pc2], %[pn2]\n\t"
      "v_mov_b32 %[pc3], %[pn3]\n\t"
      "v_add_u32 %[poff], 0x800, %[poff]\n\t"
      "v_add_u32 %[qoff], 0x800, %[qoff]\n\t"
      "buffer_load_dword %[pn0], %[poff], %[srd], 0 offen\n\t"
      "buffer_load_dword %[pn1], %[poff], %[srd], 0 offen offset:512\n\t"
      "buffer_load_dword %[pn2], %[poff], %[srd], 0 offen offset:1024\n\t"
      "buffer_load_dword %[pn3], %[poff], %[srd], 0 offen offset:1536\n\t"
      "s_sub_u32 %[cnt], %[cnt], 1\n\t"
      "s_cmp_lg_u32 %[cnt], 0\n\t"
      "s_cbranch_scc1 L_crfmain_%=\n\t"
      // E: t = 1017..1020
      STEP_S("rda", "wrb", "pc0", "0")
      STEP_S("rdb", "wra", "pc1", "512")
      STEP_S("rda", "wrb", "pc2", "1024")
      STEP_S("rdb", "wra", "pc3", "1536")
      "s_waitcnt vmcnt(4)\n\t"
      "v_mov_b32 %[pc0], %[pn0]\n\t"
      "v_mov_b32 %[pc1], %[pn1]\n\t"
      "v_mov_b32 %[pc2], %[pn2]\n\t"
      "v_add_u32 %[qoff], 0x800, %[qoff]\n\t"
      // T: t = 1021..1023
      STEP_S("rda", "wrb", "pc0", "0")
      STEP_S("rdb", "wra", "pc1", "512")
      STEP_S("rda", "wrb", "pc2", "1024")
      "s_waitcnt vmcnt(0)\n\t"
      : [pc0] "+v"(pc0), [pc1] "+v"(pc1), [pc2] "+v"(pc2), [pc3] "+v"(pc3),
        [pn0] "+v"(pn0), [pn1] "+v"(pn1), [pn2] "+v"(pn2), [pn3] "+v"(pn3),
        [qoff] "+v"(qoff), [poff] "+v"(poff), [cnt] "+s"(cnt)
      : [toff] "v"(toff), [rda] "v"(rda), [rdb] "v"(rdb),
        [wra] "v"(wra), [wrb] "v"(wrb),
        [strans] "s"(strans), [sout] "s"(sout), [srd] "s"(srd),
        [selb0] "s"(selb0), [selb1] "s"(selb1), [selb2] "s"(selb2),
        [wmask] "s"(wmask)
      : "memory", "scc",
        "v32", "v33", "v34", "v35", "v36", "v37", "v38", "v39",
        "v40", "v41", "v42", "v43", "v44", "v45", "v46", "v47",
        "v48", "v49", "v50", "v51", "v52", "v53", "v54", "v55",
        "v56", "v57", "v58", "v59", "v60", "v61", "v62", "v63",
        "v64", "v65", "v66", "v67", "v68", "v69", "v70", "v71",
        "v72", "v73", "v74", "v75", "v76", "v77", "v78", "v79",
        "v80", "v81", "v82", "v83", "v84", "v85", "v86", "v87",
        "v88", "v89", "v90", "v91", "v92", "v93", "v94", "v95",
        "v96", "v97", "v98", "v99", "v100", "v101", "v102", "v103",
        "v104", "v105", "v106", "v107", "v108", "v109", "v110", "v111",
        "v112", "v113", "v114", "v115", "v116", "v117", "v118", "v119",
        "v120", "v121", "v122", "v123", "v124", "v125", "v126", "v127");

  // ---------------- phase 2: backward chase ----------------
  __syncthreads();
  {  // transpose trans into LDS: tTp[c][l] = (T[l][c], T[64+l][c])
    const int rr = tid >> 1;
    const int h = tid & 1;
    const float4* src = (const float4*)(trans + rr * NC + h * 64);
    const int lo = rr & 63, hb = rr >> 6;
    #pragma unroll
    for (int j = 0; j < 16; ++j) {
      float4 q = src[j];
      int cb = h * 64 + 4 * j;
      tTf[(cb + 0) * 128 + lo * 2 + hb] = q.x;
      tTf[(cb + 1) * 128 + lo * 2 + hb] = q.y;
      tTf[(cb + 2) * 128 + lo * 2 + hb] = q.z;
      tTf[(cb + 3) * 128 + lo * 2 + hb] = q.w;
    }
  }
  __syncthreads();
  if (tid >= 64) return;
  const f32x2* tTp = (const f32x2*)tTf;

  // init at t = NT-1: alpha_last = q_last + pot_last; full argmax once
  float qlo_t = outb[(NT - 1) * NC + l];
  float qhi_t = outb[(NT - 1) * NC + 64 + l];
  float alo_t = qlo_t + potb[(NT - 1) * NC + l];
  float ahi_t = qhi_t + potb[(NT - 1) * NC + 64 + l];
  float m0 = wave_max_to_lane63(fmaxf(alo_t, ahi_t));
  float M0 = __int_as_float(__builtin_amdgcn_readlane(__float_as_int(m0), 63));
  unsigned long long bl = __ballot(alo_t == M0);
  unsigned long long bh = __ballot(ahi_t == M0);
  int tag = bl ? (__ffsll((long long)bl) - 1)
               : (64 + __ffsll((long long)bh) - 1);

  float cqlo[8], cqhi[8], calo[8], cahi[8];
  float nqlo[8], nqhi[8], nplo[8], nphi[8];
  #pragma unroll
  for (int j = 0; j < 8; ++j) {
    int rw = NT - 2 - j;
    cqlo[j] = outb[rw * NC + l];
    cqhi[j] = outb[rw * NC + 64 + l];
    calo[j] = cqlo[j] + potb[rw * NC + l];
    cahi[j] = cqhi[j] + potb[rw * NC + 64 + l];
  }

  for (int g = 0; g < 128; ++g) {
    #pragma unroll
    for (int j = 0; j < 8; ++j) {
      int rw = NT - 10 - 8 * g - j;
      if (rw < 0) rw = 0;
      nqlo[j] = outb[rw * NC + l];
      nqhi[j] = outb[rw * NC + 64 + l];
      nplo[j] = potb[rw * NC + l];
      nphi[j] = potb[rw * NC + 64 + l];
    }
    #pragma unroll
    for (int j = 0; j < 8; ++j) {
      int t = NT - 1 - 8 * g - j;
      if (t >= 1) {
        outb[t * NC + l]      = (l == tag) ? 1.0f : 0.0f;
        outb[t * NC + 64 + l] = (64 + l == tag) ? 1.0f : 0.0f;
        int Mlo = __builtin_amdgcn_readlane(__float_as_int(qlo_t), tag & 63);
        int Mhi = __builtin_amdgcn_readlane(__float_as_int(qhi_t), tag & 63);
        float M = __int_as_float((tag < 64) ? Mlo : Mhi);
        f32x2 tt = tTp[tag * 64 + l];
        float vlo = calo[j] + tt.x;
        float vhi = cahi[j] + tt.y;
        unsigned long long el = __ballot(vlo == M);
        unsigned long long eh = __ballot(vhi == M);
        tag = el ? (__ffsll((long long)el) - 1)
                 : (64 + __ffsll((long long)eh) - 1);
        qlo_t = cqlo[j];
        qhi_t = cqhi[j];
      }
    }
    #pragma unroll
    for (int j = 0; j < 8; ++j) {
      cqlo[j] = nqlo[j]; cqhi[j] = nqhi[j];
      calo[j] = nqlo[j] + nplo[j];
      cahi[j] = nqhi[j] + nphi[j];
    }
  }
  outb[l]      = (l == tag) ? 1.0f : 0.0f;
  outb[64 + l] = (64 + l == tag) ? 1.0f : 0.0f;
}

// ---------------- launch ----------------

extern "C" void kernel_launch(void* const* d_in, const int* in_sizes, int n_in,
                              void* d_out, int out_size, void* d_ws, size_t ws_size,
                              hipStream_t stream) {
  const float* pot   = (const float*)d_in[0];
  const float* trans = (const float*)d_in[1];
  float* out = (float*)d_out;

  constexpr int SMEM = (2 * ABUF + NC * NC) * 4;   // 67072 B
  hipFuncSetAttribute((const void*)crf_fused,
                      hipFuncAttributeMaxDynamicSharedMemorySize, SMEM);

  crf_fused<<<NB, 256, SMEM, stream>>>(pot, trans, out);
}

// Round 12
// 418.921 us; speedup vs baseline: 1.0580x; 1.0580x over previous
//
#include <hip/hip_runtime.h>

// Viterbi CRF decode: potentials [B,T,C] f32, transitions [C,C] f32 -> one-hot [B,T,C] f32
// B=256, T=1024, C=128.
//
// crf_fwd (r12 = r11 fixed): max-only DP, inline-asm inner loop, 512 threads.
//   r9 counters: DPP ~9 cyc/inst; its 16-lane reduce (16 DPP/step/lane chain)
//   dominated the step. New geometry: lane = (group g=l>>3, chunk i=l&7):
//   16 p per lane (4x ds_read_b128), 2 c per lane (32 T floats in fixed
//   v64-v95), reduce over only 8 lanes = 3 DPP rounds x 2 regs
//   (quad_perm xor1, xor2, row_half_mirror) + s_nop hazard guards.
//   r11's compile error: NO v_pk_max_f32 on gfx950 -> trees use v_max3_f32.
//   r11's latent bug fixed: tree B temps moved to v96-v111 (was clobbering
//   tree A's result).
//   Writers (l&7)<2 stash q_t (PRE-pot max) to d_out, alpha_t=q_t+pot_t to LDS.
//   Values bit-identical to r9 (same add pairing; max exactly associative).
// crf_bwd : unchanged (r4-validated): M = q_t[tag] via readlane; backpointer =
//   first p with (q+pot)+T == M (bit-exact replay) via ballot+ffs.

typedef float f32x2 __attribute__((ext_vector_type(2)));
typedef unsigned int u32x4 __attribute__((ext_vector_type(4)));

constexpr int NB = 256;
constexpr int NT = 1024;
constexpr int NC = 128;

template <int CTRL>
__device__ __forceinline__ float fmax_dpp(float v) {
  int x = __builtin_amdgcn_update_dpp(__float_as_int(v), __float_as_int(v),
                                      CTRL, 0xF, 0xF, false);
  return fmaxf(v, __int_as_float(x));
}
__device__ __forceinline__ float wave_max_to_lane63(float m) {
  m = fmax_dpp<0x111>(m);  // row_shr:1
  m = fmax_dpp<0x112>(m);  // row_shr:2
  m = fmax_dpp<0x114>(m);  // row_shr:4
  m = fmax_dpp<0x118>(m);  // row_shr:8
  m = fmax_dpp<0x142>(m);  // row_bcast:15
  m = fmax_dpp<0x143>(m);  // row_bcast:31 -> lane63 has full max
  return m;
}

// ---------------- forward ----------------
// alpha LDS: p at float index 12*(p>>3)+(p&7) (12-stride layout).
constexpr int ABUF = 192;

// tree A: alpha v48..63 (16 p) + T bank v64..79 -> max in v32
#define TREEA                                             \
  "v_pk_add_f32 v[32:33], v[48:49], v[64:65]\n\t"         \
  "v_pk_add_f32 v[34:35], v[50:51], v[66:67]\n\t"         \
  "v_pk_add_f32 v[36:37], v[52:53], v[68:69]\n\t"         \
  "v_pk_add_f32 v[38:39], v[54:55], v[70:71]\n\t"         \
  "v_pk_add_f32 v[40:41], v[56:57], v[72:73]\n\t"         \
  "v_pk_add_f32 v[42:43], v[58:59], v[74:75]\n\t"         \
  "v_pk_add_f32 v[44:45], v[60:61], v[76:77]\n\t"         \
  "v_pk_add_f32 v[46:47], v[62:63], v[78:79]\n\t"         \
  "v_max3_f32 v32, v32, v33, v34\n\t"                     \
  "v_max3_f32 v35, v35, v36, v37\n\t"                     \
  "v_max3_f32 v38, v38, v39, v40\n\t"                     \
  "v_max3_f32 v41, v41, v42, v43\n\t"                     \
  "v_max3_f32 v44, v44, v45, v46\n\t"                     \
  "v_max3_f32 v32, v32, v35, v38\n\t"                     \
  "v_max3_f32 v41, v41, v44, v47\n\t"                     \
  "v_max_f32 v32, v32, v41\n\t"

// tree B: alpha v48..63 + T bank v80..95 -> max in v96 (temps v96-v111)
#define TREEB                                             \
  "v_pk_add_f32 v[96:97], v[48:49], v[80:81]\n\t"         \
  "v_pk_add_f32 v[98:99], v[50:51], v[82:83]\n\t"         \
  "v_pk_add_f32 v[100:101], v[52:53], v[84:85]\n\t"       \
  "v_pk_add_f32 v[102:103], v[54:55], v[86:87]\n\t"       \
  "v_pk_add_f32 v[104:105], v[56:57], v[88:89]\n\t"       \
  "v_pk_add_f32 v[106:107], v[58:59], v[90:91]\n\t"       \
  "v_pk_add_f32 v[108:109], v[60:61], v[92:93]\n\t"       \
  "v_pk_add_f32 v[110:111], v[62:63], v[94:95]\n\t"       \
  "v_max3_f32 v96, v96, v97, v98\n\t"                     \
  "v_max3_f32 v99, v99, v100, v101\n\t"                   \
  "v_max3_f32 v102, v102, v103, v104\n\t"                 \
  "v_max3_f32 v105, v105, v106, v107\n\t"                 \
  "v_max3_f32 v108, v108, v109, v110\n\t"                 \
  "v_max3_f32 v96, v96, v99, v102\n\t"                    \
  "v_max3_f32 v105, v105, v108, v111\n\t"                 \
  "v_max_f32 v96, v96, v105\n\t"

#define DPP2(CTL)                                                          \
  "v_max_f32_dpp v32, v32, v32 " CTL " row_mask:0xf bank_mask:0xf\n\t"     \
  "v_max_f32_dpp v96, v96, v96 " CTL " row_mask:0xf bank_mask:0xf\n\t"

// one DP step: read buf RD, write buf WR, pot reg PC, q-store byte offset SOFF
#define STEP_S(RD, WR, PC, SOFF)                                           \
  "ds_read_b128 v[48:51], %[" RD "]\n\t"                                   \
  "ds_read_b128 v[52:55], %[" RD "] offset:16\n\t"                         \
  "ds_read_b128 v[56:59], %[" RD "] offset:48\n\t"                         \
  "ds_read_b128 v[60:63], %[" RD "] offset:64\n\t"                         \
  "s_waitcnt lgkmcnt(0)\n\t"                                               \
  TREEA                                                                    \
  TREEB                                                                    \
  "s_nop 1\n\t"                                                            \
  DPP2("quad_perm:[1,0,3,2]")                                              \
  "s_nop 0\n\t"                                                            \
  DPP2("quad_perm:[2,3,0,1]")                                              \
  "s_nop 0\n\t"                                                            \
  DPP2("row_half_mirror")                                                  \
  "s_nop 0\n\t"                                                            \
  "v_cndmask_b32 v41, v32, v96, %[selb0]\n\t"                              \
  "s_mov_b64 exec, %[wmask]\n\t"                                           \
  "v_add_f32 v40, v41, %[" PC "]\n\t"                                      \
  "ds_write_b32 %[" WR "], v40\n\t"                                        \
  "global_store_dword %[qoff], v41, %[sout] offset:" SOFF "\n\t"           \
  "s_mov_b64 exec, -1\n\t"                                                 \
  "s_waitcnt lgkmcnt(0)\n\t"                                               \
  "s_barrier\n\t"

// trans load into fixed reg R at byte offset O from toff/toff2
#define LDT(R, B, O) "global_load_dword v" R ", %[" B "], %[strans] offset:" O "\n\t"

__global__ __launch_bounds__(512, 2)
void crf_fwd(const float* __restrict__ pot, const float* __restrict__ trans,
             float* __restrict__ out) {
  __shared__ __align__(16) float alpha[2 * ABUF];

  const int tid = threadIdx.x;
  const int b = blockIdx.x;
  const int w = tid >> 6;          // wave 0..7
  const int l = tid & 63;          // lane
  const int g = l >> 3;            // 8-lane group 0..7
  const int i = l & 7;             // p-chunk (p = 16i..16i+15)
  const int G = w * 8 + g;         // c-pair index 0..63 (c0 = 2G)
  const bool wr = (l & 7) < 2;     // writer lanes: (l&7)==0 -> c0, ==1 -> c1
  const int cw = 16 * w + 2 * g + (l & 1);     // writer's c (valid all lanes)
  const int widx = 12 * (cw >> 3) + (cw & 7);  // writer's LDS float index

  const float* potb = pot + (size_t)b * NT * NC;
  float* outb = out + (size_t)b * NT * NC;

  // LDS byte addresses
  unsigned rda = (unsigned)(size_t)(alpha + 24 * i);
  unsigned rdb = (unsigned)(size_t)(alpha + ABUF + 24 * i);
  unsigned wra = (unsigned)(size_t)(alpha + widx);
  unsigned wrb = (unsigned)(size_t)(alpha + ABUF + widx);

  // trans: v[64+j] = T[16i+j][c0] (j=0..7), v[72+j] = T[16i+8+j][c0];
  //        v[80..95] same for column c0+1.   (c0 = 2G)
  unsigned toff  = (unsigned)((16 * i * NC + 2 * G) * 4);
  unsigned toff2 = toff + 4096;
  unsigned qoff = (unsigned)((1 * NC + cw) * 4);                 // q row 1
  unsigned poff = ((unsigned)b * (NT * NC) + 5 * NC + cw) * 4u;  // pot row 5
  unsigned long long strans = (unsigned long long)(size_t)trans;
  unsigned long long sout = (unsigned long long)(size_t)outb;
  unsigned long long pbase = (unsigned long long)(size_t)pot;
  u32x4 srd;
  srd.x = (unsigned)pbase;
  srd.y = (unsigned)(pbase >> 32) & 0xFFFFu;
  srd.z = (unsigned)(NB * NT * NC) * 4u;     // bounds: OOB load -> 0
  srd.w = 0x00020000u;
  unsigned long long selb0 = 0xAAAAAAAAAAAAAAAAull;  // lanes with l&1
  unsigned long long wmask = 0x0303030303030303ull;  // lanes with (l&7)<2
  int cnt = 254;

  float pc0 = potb[1 * NC + cw], pc1 = potb[2 * NC + cw];
  float pc2 = potb[3 * NC + cw], pc3 = potb[4 * NC + cw];
  float pn0 = 0.f, pn1 = 0.f, pn2 = 0.f, pn3 = 0.f;

  if (wr) {
    alpha[widx] = potb[cw];   // alpha_0 = pot[:,0,:]
    outb[cw] = 0.0f;          // q_0 := 0  (alpha_0 = 0 + pot_0)
  }
  __syncthreads();

  asm volatile(
      // ---- trans -> fixed v64..v95 ----
      LDT("64","toff","0")     LDT("65","toff","512")
      LDT("66","toff","1024")  LDT("67","toff","1536")
      LDT("68","toff","2048")  LDT("69","toff","2560")
      LDT("70","toff","3072")  LDT("71","toff","3584")
      LDT("72","toff2","0")    LDT("73","toff2","512")
      LDT("74","toff2","1024") LDT("75","toff2","1536")
      LDT("76","toff2","2048") LDT("77","toff2","2560")
      LDT("78","toff2","3072") LDT("79","toff2","3584")
      LDT("80","toff","4")     LDT("81","toff","516")
      LDT("82","toff","1028")  LDT("83","toff","1540")
      LDT("84","toff","2052")  LDT("85","toff","2564")
      LDT("86","toff","3076")  LDT("87","toff","3588")
      LDT("88","toff2","4")    LDT("89","toff2","516")
      LDT("90","toff2","1028") LDT("91","toff2","1540")
      LDT("92","toff2","2052") LDT("93","toff2","2564")
      LDT("94","toff2","3076") LDT("95","toff2","3588")
      "s_waitcnt vmcnt(0)\n\t"
      // ---- pot prefetch rows 5..8 ----
      "buffer_load_dword %[pn0], %[poff], %[srd], 0 offen\n\t"
      "buffer_load_dword %[pn1], %[poff], %[srd], 0 offen offset:512\n\t"
      "buffer_load_dword %[pn2], %[poff], %[srd], 0 offen offset:1024\n\t"
      "buffer_load_dword %[pn3], %[poff], %[srd], 0 offen offset:1536\n\t"
      "L_crfmain_%=:\n\t"
      STEP_S("rda", "wrb", "pc0", "0")
      STEP_S("rdb", "wra", "pc1", "512")
      STEP_S("rda", "wrb", "pc2", "1024")
      STEP_S("rdb", "wra", "pc3", "1536")
      "s_waitcnt vmcnt(4)\n\t"
      "v_mov_b32 %[pc0], %[pn0]\n\t"
      "v_mov_b32 %[pc1], %[pn1]\n\t"
      "v_mov_b32 %[pc2], %[pn2]\n\t"
      "v_mov_b32 %[pc3], %[pn3]\n\t"
      "v_add_u32 %[poff], 0x800, %[poff]\n\t"
      "v_add_u32 %[qoff], 0x800, %[qoff]\n\t"
      "buffer_load_dword %[pn0], %[poff], %[srd], 0 offen\n\t"
      "buffer_load_dword %[pn1], %[poff], %[srd], 0 offen offset:512\n\t"
      "buffer_load_dword %[pn2], %[poff], %[srd], 0 offen offset:1024\n\t"
      "buffer_load_dword %[pn3], %[poff], %[srd], 0 offen offset:1536\n\t"
      "s_sub_u32 %[cnt], %[cnt], 1\n\t"
      "s_cmp_lg_u32 %[cnt], 0\n\t"
      "s_cbranch_scc1 L_crfmain_%=\n\t"
      // E: t = 1017..1020
      STEP_S("rda", "wrb", "pc0", "0")
      STEP_S("rdb", "wra", "pc1", "512")
      STEP_S("rda", "wrb", "pc2", "1024")
      STEP_S("rdb", "wra", "pc3", "1536")
      "s_waitcnt vmcnt(4)\n\t"
      "v_mov_b32 %[pc0], %[pn0]\n\t"
      "v_mov_b32 %[pc1], %[pn1]\n\t"
      "v_mov_b32 %[pc2], %[pn2]\n\t"
      "v_add_u32 %[qoff], 0x800, %[qoff]\n\t"
      // T: t = 1021..1023
      STEP_S("rda", "wrb", "pc0", "0")
      STEP_S("rdb", "wra", "pc1", "512")
      STEP_S("rda", "wrb", "pc2", "1024")
      : [pc0] "+v"(pc0), [pc1] "+v"(pc1), [pc2] "+v"(pc2), [pc3] "+v"(pc3),
        [pn0] "+v"(pn0), [pn1] "+v"(pn1), [pn2] "+v"(pn2), [pn3] "+v"(pn3),
        [qoff] "+v"(qoff), [poff] "+v"(poff), [cnt] "+s"(cnt)
      : [toff] "v"(toff), [toff2] "v"(toff2),
        [rda] "v"(rda), [rdb] "v"(rdb), [wra] "v"(wra), [wrb] "v"(wrb),
        [strans] "s"(strans), [sout] "s"(sout), [srd] "s"(srd),
        [selb0] "s"(selb0), [wmask] "s"(wmask)
      : "memory", "scc",
        "v32", "v33", "v34", "v35", "v36", "v37", "v38", "v39",
        "v40", "v41", "v42", "v43", "v44", "v45", "v46", "v47",
        "v48", "v49", "v50", "v51", "v52", "v53", "v54", "v55",
        "v56", "v57", "v58", "v59", "v60", "v61", "v62", "v63",
        "v64", "v65", "v66", "v67", "v68", "v69", "v70", "v71",
        "v72", "v73", "v74", "v75", "v76", "v77", "v78", "v79",
        "v80", "v81", "v82", "v83", "v84", "v85", "v86", "v87",
        "v88", "v89", "v90", "v91", "v92", "v93", "v94", "v95",
        "v96", "v97", "v98", "v99", "v100", "v101", "v102", "v103",
        "v104", "v105", "v106", "v107", "v108", "v109", "v110", "v111");
}

// ---------------- backward ----------------
// tTp[c][l] = (T[l][c], T[64+l][c]) as float2 in LDS (64 KiB).
// Wave 0 chases; per step only an equality scan against M = q_t[tag].

__global__ __launch_bounds__(256)
void crf_bwd(const float* __restrict__ pot, const float* __restrict__ trans,
             float* __restrict__ out) {
  extern __shared__ float tTf[];   // float2[NC][64] interleaved
  const int tid = threadIdx.x;
  const int b = blockIdx.x;
  const float* potb = pot + (size_t)b * NT * NC;
  float* outb = out + (size_t)b * NT * NC;

  {
    const int rr = tid >> 1;   // source row p of trans
    const int h = tid & 1;     // which half of the row
    const float4* src = (const float4*)(trans + rr * NC + h * 64);
    const int lo = rr & 63, hb = rr >> 6;
    #pragma unroll
    for (int j = 0; j < 16; ++j) {
      float4 q = src[j];
      int cb = h * 64 + 4 * j;
      tTf[(cb + 0) * 128 + lo * 2 + hb] = q.x;
      tTf[(cb + 1) * 128 + lo * 2 + hb] = q.y;
      tTf[(cb + 2) * 128 + lo * 2 + hb] = q.z;
      tTf[(cb + 3) * 128 + lo * 2 + hb] = q.w;
    }
  }
  __syncthreads();
  if (tid >= 64) return;
  const int l = tid;
  const f32x2* tTp = (const f32x2*)tTf;

  // init at t = NT-1: alpha_last = q_last + pot_last; full argmax once
  float qlo_t = outb[(NT - 1) * NC + l];
  float qhi_t = outb[(NT - 1) * NC + 64 + l];
  float alo_t = qlo_t + potb[(NT - 1) * NC + l];
  float ahi_t = qhi_t + potb[(NT - 1) * NC + 64 + l];
  float m0 = wave_max_to_lane63(fmaxf(alo_t, ahi_t));
  float M0 = __int_as_float(__builtin_amdgcn_readlane(__float_as_int(m0), 63));
  unsigned long long bl = __ballot(alo_t == M0);
  unsigned long long bh = __ballot(ahi_t == M0);
  int tag = bl ? (__ffsll((long long)bl) - 1)
               : (64 + __ffsll((long long)bh) - 1);

  // prefetch rows 1022..1015 (q and pot), precompute alpha
  float cqlo[8], cqhi[8], calo[8], cahi[8];
  float nqlo[8], nqhi[8], nplo[8], nphi[8];
  #pragma unroll
  for (int j = 0; j < 8; ++j) {
    int rw = NT - 2 - j;
    cqlo[j] = outb[rw * NC + l];
    cqhi[j] = outb[rw * NC + 64 + l];
    calo[j] = cqlo[j] + potb[rw * NC + l];
    cahi[j] = cqhi[j] + potb[rw * NC + 64 + l];
  }

  for (int g = 0; g < 128; ++g) {
    #pragma unroll
    for (int j = 0; j < 8; ++j) {      // prefetch group g+1
      int rw = NT - 10 - 8 * g - j;
      if (rw < 0) rw = 0;
      nqlo[j] = outb[rw * NC + l];
      nqhi[j] = outb[rw * NC + 64 + l];
      nplo[j] = potb[rw * NC + l];
      nphi[j] = potb[rw * NC + 64 + l];
    }
    #pragma unroll
    for (int j = 0; j < 8; ++j) {
      int t = NT - 1 - 8 * g - j;
      if (t >= 1) {
        outb[t * NC + l]      = (l == tag) ? 1.0f : 0.0f;
        outb[t * NC + 64 + l] = (64 + l == tag) ? 1.0f : 0.0f;
        int Mlo = __builtin_amdgcn_readlane(__float_as_int(qlo_t), tag & 63);
        int Mhi = __builtin_amdgcn_readlane(__float_as_int(qhi_t), tag & 63);
        float M = __int_as_float((tag < 64) ? Mlo : Mhi);
        f32x2 tt = tTp[tag * 64 + l];
        float vlo = calo[j] + tt.x;
        float vhi = cahi[j] + tt.y;
        unsigned long long el = __ballot(vlo == M);
        unsigned long long eh = __ballot(vhi == M);
        tag = el ? (__ffsll((long long)el) - 1)
                 : (64 + __ffsll((long long)eh) - 1);
        qlo_t = cqlo[j];
        qhi_t = cqhi[j];
      }
    }
    #pragma unroll
    for (int j = 0; j < 8; ++j) {
      cqlo[j] = nqlo[j]; cqhi[j] = nqhi[j];
      calo[j] = nqlo[j] + nplo[j];
      cahi[j] = nqhi[j] + nphi[j];
    }
  }
  outb[l]      = (l == tag) ? 1.0f : 0.0f;
  outb[64 + l] = (64 + l == tag) ? 1.0f : 0.0f;
}

// ---------------- launch ----------------

extern "C" void kernel_launch(void* const* d_in, const int* in_sizes, int n_in,
                              void* d_out, int out_size, void* d_ws, size_t ws_size,
                              hipStream_t stream) {
  const float* pot   = (const float*)d_in[0];
  const float* trans = (const float*)d_in[1];
  float* out = (float*)d_out;

  hipFuncSetAttribute((const void*)crf_bwd,
                      hipFuncAttributeMaxDynamicSharedMemorySize, NC * NC * 4);

  crf_fwd<<<NB, 512, 0, stream>>>(pot, trans, out);
  crf_bwd<<<NB, 256, NC * NC * 4, stream>>>(pot, trans, out);
}

// Round 13
// 413.958 us; speedup vs baseline: 1.0707x; 1.0120x over previous
//
#include <hip/hip_runtime.h>

// Viterbi CRF decode: potentials [B,T,C] f32, transitions [C,C] f32 -> one-hot [B,T,C] f32
// B=256, T=1024, C=128.
//
// r13: ONE fused kernel (512 thr / 8 waves), 1 block = 1 batch = 1 CU.
//  Phase 1 (fwd, inline asm; r12 core + chain trims): max-only DP, L=8 groups:
//   lane (g=l>>3, i=l&7): 16 p/lane (4x ds_read_b128, 12-stride LDS), 2 c/lane
//   (32 T floats pinned in v64-v95). Trees split into p-halves: first 8 pk_adds
//   start at lgkmcnt(2), rest at lgkmcnt(0); A/B max3 chains pairwise
//   interleaved (no dep stalls). 3 DPP rounds (quad_perm xor1/xor2 +
//   row_half_mirror). Writers (l&7)<2 stash q_t (PRE-pot max) to d_out and
//   alpha_t = q_t + pot_t to LDS. Values bit-identical to r12 (max is exactly
//   associative; same add pairing).
//  Phase 2 (bwd, C; r4-validated): transpose T into LDS; wave 0 chases:
//   M = q_t[tag] via readlane; backpointer = first p with (q+pot)+T == M
//   (bit-exact replay) via ballot+ffs; one-hot overwrites d_out.
//  Fusion validated by r10 (same q-store -> vmcnt(0) -> same-CU read pattern).

typedef float f32x2 __attribute__((ext_vector_type(2)));
typedef unsigned int u32x4 __attribute__((ext_vector_type(4)));

constexpr int NB = 256;
constexpr int NT = 1024;
constexpr int NC = 128;

template <int CTRL>
__device__ __forceinline__ float fmax_dpp(float v) {
  int x = __builtin_amdgcn_update_dpp(__float_as_int(v), __float_as_int(v),
                                      CTRL, 0xF, 0xF, false);
  return fmaxf(v, __int_as_float(x));
}
__device__ __forceinline__ float wave_max_to_lane63(float m) {
  m = fmax_dpp<0x111>(m);  // row_shr:1
  m = fmax_dpp<0x112>(m);  // row_shr:2
  m = fmax_dpp<0x114>(m);  // row_shr:4
  m = fmax_dpp<0x118>(m);  // row_shr:8
  m = fmax_dpp<0x142>(m);  // row_bcast:15
  m = fmax_dpp<0x143>(m);  // row_bcast:31 -> lane63 has full max
  return m;
}

// ---------------- forward ----------------
// alpha LDS: p at float index 12*(p>>3)+(p&7) (12-stride layout).
constexpr int ABUF = 192;

#define DPP2(CTL)                                                          \
  "v_max_f32_dpp v32, v32, v32 " CTL " row_mask:0xf bank_mask:0xf\n\t"     \
  "v_max_f32_dpp v96, v96, v96 " CTL " row_mask:0xf bank_mask:0xf\n\t"

// one DP step: read buf RD, write buf WR, pot reg PC, q-store byte offset SOFF.
// Trees interleaved A/B and split by p-halves; half-1 starts at lgkmcnt(2).
#define STEP_S(RD, WR, PC, SOFF)                                           \
  "ds_read_b128 v[48:51], %[" RD "]\n\t"                                   \
  "ds_read_b128 v[52:55], %[" RD "] offset:16\n\t"                         \
  "ds_read_b128 v[56:59], %[" RD "] offset:48\n\t"                         \
  "ds_read_b128 v[60:63], %[" RD "] offset:64\n\t"                         \
  "s_waitcnt lgkmcnt(2)\n\t"                                               \
  "v_pk_add_f32 v[32:33], v[48:49], v[64:65]\n\t"                          \
  "v_pk_add_f32 v[96:97], v[48:49], v[80:81]\n\t"                          \
  "v_pk_add_f32 v[34:35], v[50:51], v[66:67]\n\t"                          \
  "v_pk_add_f32 v[98:99], v[50:51], v[82:83]\n\t"                          \
  "v_pk_add_f32 v[36:37], v[52:53], v[68:69]\n\t"                          \
  "v_pk_add_f32 v[100:101], v[52:53], v[84:85]\n\t"                        \
  "v_pk_add_f32 v[38:39], v[54:55], v[70:71]\n\t"                          \
  "v_pk_add_f32 v[102:103], v[54:55], v[86:87]\n\t"                        \
  "v_max3_f32 v32, v32, v33, v34\n\t"                                      \
  "v_max3_f32 v96, v96, v97, v98\n\t"                                      \
  "v_max3_f32 v35, v35, v36, v37\n\t"                                      \
  "v_max3_f32 v99, v99, v100, v101\n\t"                                    \
  "s_waitcnt lgkmcnt(0)\n\t"                                               \
  "v_pk_add_f32 v[40:41], v[56:57], v[72:73]\n\t"                          \
  "v_pk_add_f32 v[104:105], v[56:57], v[88:89]\n\t"                        \
  "v_pk_add_f32 v[42:43], v[58:59], v[74:75]\n\t"                          \
  "v_pk_add_f32 v[106:107], v[58:59], v[90:91]\n\t"                        \
  "v_pk_add_f32 v[44:45], v[60:61], v[76:77]\n\t"                          \
  "v_pk_add_f32 v[108:109], v[60:61], v[92:93]\n\t"                        \
  "v_pk_add_f32 v[46:47], v[62:63], v[78:79]\n\t"                          \
  "v_pk_add_f32 v[110:111], v[62:63], v[94:95]\n\t"                        \
  "v_max3_f32 v38, v38, v39, v40\n\t"                                      \
  "v_max3_f32 v102, v102, v103, v104\n\t"                                  \
  "v_max3_f32 v41, v41, v42, v43\n\t"                                      \
  "v_max3_f32 v105, v105, v106, v107\n\t"                                  \
  "v_max3_f32 v44, v44, v45, v46\n\t"                                      \
  "v_max3_f32 v108, v108, v109, v110\n\t"                                  \
  "v_max3_f32 v32, v32, v35, v38\n\t"                                      \
  "v_max3_f32 v96, v96, v99, v102\n\t"                                     \
  "v_max3_f32 v41, v41, v44, v47\n\t"                                      \
  "v_max3_f32 v105, v105, v108, v111\n\t"                                  \
  "v_max_f32 v32, v32, v41\n\t"                                            \
  "v_max_f32 v96, v96, v105\n\t"                                           \
  "s_nop 1\n\t"                                                            \
  DPP2("quad_perm:[1,0,3,2]")                                              \
  "s_nop 0\n\t"                                                            \
  DPP2("quad_perm:[2,3,0,1]")                                              \
  "s_nop 0\n\t"                                                            \
  DPP2("row_half_mirror")                                                  \
  "s_nop 0\n\t"                                                            \
  "v_cndmask_b32 v41, v32, v96, %[selb0]\n\t"                              \
  "s_mov_b64 exec, %[wmask]\n\t"                                           \
  "v_add_f32 v40, v41, %[" PC "]\n\t"                                      \
  "ds_write_b32 %[" WR "], v40\n\t"                                        \
  "global_store_dword %[qoff], v41, %[sout] offset:" SOFF "\n\t"           \
  "s_mov_b64 exec, -1\n\t"                                                 \
  "s_waitcnt lgkmcnt(0)\n\t"                                               \
  "s_barrier\n\t"

// trans load into fixed reg R at byte offset O from toff/toff2
#define LDT(R, B, O) "global_load_dword v" R ", %[" B "], %[strans] offset:" O "\n\t"

__global__ __launch_bounds__(512)
void crf_fused(const float* __restrict__ pot, const float* __restrict__ trans,
               float* __restrict__ out) {
  extern __shared__ __align__(16) float smem[];
  float* alpha = smem;            // 2*ABUF floats (1.5 KB)
  float* tTf = smem + 2 * ABUF;   // 16384 floats (64 KB), phase 2

  const int tid = threadIdx.x;
  const int b = blockIdx.x;
  const int w = tid >> 6;          // wave 0..7
  const int l = tid & 63;          // lane
  const int g = l >> 3;            // 8-lane group 0..7
  const int i = l & 7;             // p-chunk (p = 16i..16i+15)
  const int G = w * 8 + g;         // c-pair index 0..63 (c0 = 2G)
  const bool wr = (l & 7) < 2;     // writer lanes: (l&7)==0 -> c0, ==1 -> c1
  const int cw = 16 * w + 2 * g + (l & 1);     // writer's c (valid all lanes)
  const int widx = 12 * (cw >> 3) + (cw & 7);  // writer's LDS float index

  const float* potb = pot + (size_t)b * NT * NC;
  float* outb = out + (size_t)b * NT * NC;

  // ---------------- phase 1: forward DP ----------------
  unsigned rda = (unsigned)(size_t)(alpha + 24 * i);
  unsigned rdb = (unsigned)(size_t)(alpha + ABUF + 24 * i);
  unsigned wra = (unsigned)(size_t)(alpha + widx);
  unsigned wrb = (unsigned)(size_t)(alpha + ABUF + widx);

  // trans: v[64+j] = T[16i+j][c0] (j=0..7), v[72+j] = T[16i+8+j][c0];
  //        v[80..95] same for column c0+1.   (c0 = 2G)
  unsigned toff  = (unsigned)((16 * i * NC + 2 * G) * 4);
  unsigned toff2 = toff + 4096;
  unsigned qoff = (unsigned)((1 * NC + cw) * 4);                 // q row 1
  unsigned poff = ((unsigned)b * (NT * NC) + 5 * NC + cw) * 4u;  // pot row 5
  unsigned long long strans = (unsigned long long)(size_t)trans;
  unsigned long long sout = (unsigned long long)(size_t)outb;
  unsigned long long pbase = (unsigned long long)(size_t)pot;
  u32x4 srd;
  srd.x = (unsigned)pbase;
  srd.y = (unsigned)(pbase >> 32) & 0xFFFFu;
  srd.z = (unsigned)(NB * NT * NC) * 4u;     // bounds: OOB load -> 0
  srd.w = 0x00020000u;
  unsigned long long selb0 = 0xAAAAAAAAAAAAAAAAull;  // lanes with l&1
  unsigned long long wmask = 0x0303030303030303ull;  // lanes with (l&7)<2
  int cnt = 254;

  float pc0 = potb[1 * NC + cw], pc1 = potb[2 * NC + cw];
  float pc2 = potb[3 * NC + cw], pc3 = potb[4 * NC + cw];
  float pn0 = 0.f, pn1 = 0.f, pn2 = 0.f, pn3 = 0.f;

  if (wr) {
    alpha[widx] = potb[cw];   // alpha_0 = pot[:,0,:]
    outb[cw] = 0.0f;          // q_0 := 0  (alpha_0 = 0 + pot_0)
  }
  __syncthreads();

  asm volatile(
      // ---- trans -> fixed v64..v95 ----
      LDT("64","toff","0")     LDT("65","toff","512")
      LDT("66","toff","1024")  LDT("67","toff","1536")
      LDT("68","toff","2048")  LDT("69","toff","2560")
      LDT("70","toff","3072")  LDT("71","toff","3584")
      LDT("72","toff2","0")    LDT("73","toff2","512")
      LDT("74","toff2","1024") LDT("75","toff2","1536")
      LDT("76","toff2","2048") LDT("77","toff2","2560")
      LDT("78","toff2","3072") LDT("79","toff2","3584")
      LDT("80","toff","4")     LDT("81","toff","516")
      LDT("82","toff","1028")  LDT("83","toff","1540")
      LDT("84","toff","2052")  LDT("85","toff","2564")
      LDT("86","toff","3076")  LDT("87","toff","3588")
      LDT("88","toff2","4")    LDT("89","toff2","516")
      LDT("90","toff2","1028") LDT("91","toff2","1540")
      LDT("92","toff2","2052") LDT("93","toff2","2564")
      LDT("94","toff2","3076") LDT("95","toff2","3588")
      "s_waitcnt vmcnt(0)\n\t"
      // ---- pot prefetch rows 5..8 ----
      "buffer_load_dword %[pn0], %[poff], %[srd], 0 offen\n\t"
      "buffer_load_dword %[pn1], %[poff], %[srd], 0 offen offset:512\n\t"
      "buffer_load_dword %[pn2], %[poff], %[srd], 0 offen offset:1024\n\t"
      "buffer_load_dword %[pn3], %[poff], %[srd], 0 offen offset:1536\n\t"
      "L_crfmain_%=:\n\t"
      STEP_S("rda", "wrb", "pc0", "0")
      STEP_S("rdb", "wra", "pc1", "512")
      STEP_S("rda", "wrb", "pc2", "1024")
      STEP_S("rdb", "wra", "pc3", "1536")
      "s_waitcnt vmcnt(4)\n\t"
      "v_mov_b32 %[pc0], %[pn0]\n\t"
      "v_mov_b32 %[pc1], %[pn1]\n\t"
      "v_mov_b32 %[pc2], %[pn2]\n\t"
      "v_mov_b32 %[pc3], %[pn3]\n\t"
      "v_add_u32 %[poff], 0x800, %[poff]\n\t"
      "v_add_u32 %[qoff], 0x800, %[qoff]\n\t"
      "buffer_load_dword %[pn0], %[poff], %[srd], 0 offen\n\t"
      "buffer_load_dword %[pn1], %[poff], %[srd], 0 offen offset:512\n\t"
      "buffer_load_dword %[pn2], %[poff], %[srd], 0 offen offset:1024\n\t"
      "buffer_load_dword %[pn3], %[poff], %[srd], 0 offen offset:1536\n\t"
      "s_sub_u32 %[cnt], %[cnt], 1\n\t"
      "s_cmp_lg_u32 %[cnt], 0\n\t"
      "s_cbranch_scc1 L_crfmain_%=\n\t"
      // E: t = 1017..1020
      STEP_S("rda", "wrb", "pc0", "0")
      STEP_S("rdb", "wra", "pc1", "512")
      STEP_S("rda", "wrb", "pc2", "1024")
      STEP_S("rdb", "wra", "pc3", "1536")
      "s_waitcnt vmcnt(4)\n\t"
      "v_mov_b32 %[pc0], %[pn0]\n\t"
      "v_mov_b32 %[pc1], %[pn1]\n\t"
      "v_mov_b32 %[pc2], %[pn2]\n\t"
      "v_add_u32 %[qoff], 0x800, %[qoff]\n\t"
      // T: t = 1021..1023
      STEP_S("rda", "wrb", "pc0", "0")
      STEP_S("rdb", "wra", "pc1", "512")
      STEP_S("rda", "wrb", "pc2", "1024")
      "s_waitcnt vmcnt(0)\n\t"
      : [pc0] "+v"(pc0), [pc1] "+v"(pc1), [pc2] "+v"(pc2), [pc3] "+v"(pc3),
        [pn0] "+v"(pn0), [pn1] "+v"(pn1), [pn2] "+v"(pn2), [pn3] "+v"(pn3),
        [qoff] "+v"(qoff), [poff] "+v"(poff), [cnt] "+s"(cnt)
      : [toff] "v"(toff), [toff2] "v"(toff2),
        [rda] "v"(rda), [rdb] "v"(rdb), [wra] "v"(wra), [wrb] "v"(wrb),
        [strans] "s"(strans), [sout] "s"(sout), [srd] "s"(srd),
        [selb0] "s"(selb0), [wmask] "s"(wmask)
      : "memory", "scc",
        "v32", "v33", "v34", "v35", "v36", "v37", "v38", "v39",
        "v40", "v41", "v42", "v43", "v44", "v45", "v46", "v47",
        "v48", "v49", "v50", "v51", "v52", "v53", "v54", "v55",
        "v56", "v57", "v58", "v59", "v60", "v61", "v62", "v63",
        "v64", "v65", "v66", "v67", "v68", "v69", "v70", "v71",
        "v72", "v73", "v74", "v75", "v76", "v77", "v78", "v79",
        "v80", "v81", "v82", "v83", "v84", "v85", "v86", "v87",
        "v88", "v89", "v90", "v91", "v92", "v93", "v94", "v95",
        "v96", "v97", "v98", "v99", "v100", "v101", "v102", "v103",
        "v104", "v105", "v106", "v107", "v108", "v109", "v110", "v111");

  // ---------------- phase 2: backward chase ----------------
  __syncthreads();
  {  // transpose trans into LDS: tTp[c][l] = (T[l][c], T[64+l][c]); 512 threads
    const int rr = tid >> 2;   // source row p 0..127
    const int q4 = tid & 3;    // quarter of the row
    const float4* src = (const float4*)(trans + rr * NC + q4 * 32);
    const int lo = rr & 63, hb = rr >> 6;
    #pragma unroll
    for (int j = 0; j < 8; ++j) {
      float4 qv = src[j];
      int cb = q4 * 32 + 4 * j;
      tTf[(cb + 0) * 128 + lo * 2 + hb] = qv.x;
      tTf[(cb + 1) * 128 + lo * 2 + hb] = qv.y;
      tTf[(cb + 2) * 128 + lo * 2 + hb] = qv.z;
      tTf[(cb + 3) * 128 + lo * 2 + hb] = qv.w;
    }
  }
  __syncthreads();
  if (tid >= 64) return;
  const f32x2* tTp = (const f32x2*)tTf;

  // init at t = NT-1: alpha_last = q_last + pot_last; full argmax once
  float qlo_t = outb[(NT - 1) * NC + l];
  float qhi_t = outb[(NT - 1) * NC + 64 + l];
  float alo_t = qlo_t + potb[(NT - 1) * NC + l];
  float ahi_t = qhi_t + potb[(NT - 1) * NC + 64 + l];
  float m0 = wave_max_to_lane63(fmaxf(alo_t, ahi_t));
  float M0 = __int_as_float(__builtin_amdgcn_readlane(__float_as_int(m0), 63));
  unsigned long long bl = __ballot(alo_t == M0);
  unsigned long long bh = __ballot(ahi_t == M0);
  int tag = bl ? (__ffsll((long long)bl) - 1)
               : (64 + __ffsll((long long)bh) - 1);

  // prefetch rows 1022..1015 (q and pot), precompute alpha
  float cqlo[8], cqhi[8], calo[8], cahi[8];
  float nqlo[8], nqhi[8], nplo[8], nphi[8];
  #pragma unroll
  for (int j = 0; j < 8; ++j) {
    int rw = NT - 2 - j;
    cqlo[j] = outb[rw * NC + l];
    cqhi[j] = outb[rw * NC + 64 + l];
    calo[j] = cqlo[j] + potb[rw * NC + l];
    cahi[j] = cqhi[j] + potb[rw * NC + 64 + l];
  }

  for (int g2 = 0; g2 < 128; ++g2) {
    #pragma unroll
    for (int j = 0; j < 8; ++j) {      // prefetch group g2+1
      int rw = NT - 10 - 8 * g2 - j;
      if (rw < 0) rw = 0;
      nqlo[j] = outb[rw * NC + l];
      nqhi[j] = outb[rw * NC + 64 + l];
      nplo[j] = potb[rw * NC + l];
      nphi[j] = potb[rw * NC + 64 + l];
    }
    #pragma unroll
    for (int j = 0; j < 8; ++j) {
      int t = NT - 1 - 8 * g2 - j;
      if (t >= 1) {
        outb[t * NC + l]      = (l == tag) ? 1.0f : 0.0f;
        outb[t * NC + 64 + l] = (64 + l == tag) ? 1.0f : 0.0f;
        int Mlo = __builtin_amdgcn_readlane(__float_as_int(qlo_t), tag & 63);
        int Mhi = __builtin_amdgcn_readlane(__float_as_int(qhi_t), tag & 63);
        float M = __int_as_float((tag < 64) ? Mlo : Mhi);
        f32x2 tt = tTp[tag * 64 + l];
        float vlo = calo[j] + tt.x;
        float vhi = cahi[j] + tt.y;
        unsigned long long el = __ballot(vlo == M);
        unsigned long long eh = __ballot(vhi == M);
        tag = el ? (__ffsll((long long)el) - 1)
                 : (64 + __ffsll((long long)eh) - 1);
        qlo_t = cqlo[j];
        qhi_t = cqhi[j];
      }
    }
    #pragma unroll
    for (int j = 0; j < 8; ++j) {
      cqlo[j] = nqlo[j]; cqhi[j] = nqhi[j];
      calo[j] = nqlo[j] + nplo[j];
      cahi[j] = nqhi[j] + nphi[j];
    }
  }
  outb[l]      = (l == tag) ? 1.0f : 0.0f;
  outb[64 + l] = (64 + l == tag) ? 1.0f : 0.0f;
}

// ---------------- launch ----------------

extern "C" void kernel_launch(void* const* d_in, const int* in_sizes, int n_in,
                              void* d_out, int out_size, void* d_ws, size_t ws_size,
                              hipStream_t stream) {
  const float* pot   = (const float*)d_in[0];
  const float* trans = (const float*)d_in[1];
  float* out = (float*)d_out;

  constexpr int SMEM = (2 * ABUF + NC * NC) * 4;   // 67072 B
  hipFuncSetAttribute((const void*)crf_fused,
                      hipFuncAttributeMaxDynamicSharedMemorySize, SMEM);

  crf_fused<<<NB, 512, SMEM, stream>>>(pot, trans, out);
}